// Round 8
// baseline (353.387 us; speedup 1.0000x reference)
//
#include <hip/hip_runtime.h>
#include <hip/hip_bf16.h>
#include <hip/hip_cooperative_groups.h>
#include <stdint.h>

namespace cg = cooperative_groups;

#define IN_F 4096
#define OUT_F 11008
#define TOKENS 32
#define NELEM_W (OUT_F * IN_F)       // 45088768 weights, ~180 MB fp32
#define NBLK 256                     // persistent blocks — 1/CU, launch can't fail
#define NOG 688                      // OUT_F / 16 output tiles

typedef __attribute__((ext_vector_type(8))) __bf16 bf16x8;
typedef __attribute__((ext_vector_type(4))) float  f32x4;

// d_ws layout (bytes):
//   [0, 1024):     apart — 256 per-block |w| partial sums (f32)
//   [4096, +256K): xb    — x converted to bf16
#define APART_OFF 0
#define XB_OFF    4096

// fp32 -> bf16 bits (round-to-nearest-even), result in low 16
__device__ __forceinline__ uint32_t bfr(float v) {
    uint32_t u = __float_as_uint(v);
    uint32_t r = u + 0x7FFFu + ((u >> 16) & 1u);
    return r >> 16;
}

// ---------------- ternarize helpers (verified R5/R6 math) ----------------
__device__ __forceinline__ uint32_t tern1(float v, float thr) {
    uint32_t u  = __float_as_uint(v);
    uint32_t pm = (u & 0x80000000u) | 0x3F800000u;   // +-1.0f
    return (__builtin_fabsf(v) > thr) ? pm : 0u;
}

__device__ __forceinline__ uint2 tern4(float4 b, float thr) {
    uint32_t q0 = tern1(b.x, thr), q1 = tern1(b.y, thr);
    uint32_t q2 = tern1(b.z, thr), q3 = tern1(b.w, thr);
    uint2 r;
    r.x = __builtin_amdgcn_perm(q1, q0, 0x07060302u);
    r.y = __builtin_amdgcn_perm(q3, q2, 0x07060302u);
    return r;
}

// ---------------- single cooperative persistent kernel ----------------
// 256 blocks x 256 threads (4 waves) — one block per CU, co-residency trivially
// satisfied, so hipLaunchCooperativeKernel cannot reject the grid.
// Phase A: grid-stride |w| sum (+ x->bf16 in blocks 0-63), per-block partial.
// grid.sync()
// Phase B: reduce 256 partials -> thr/scale, then loop og tiles (2-3 per
// block): LDS-staged ternary MFMA GEMM (wave wv covers k in [wv*1024,+1024),
// 16 chunks of 64, 2-deep register double-buffer), direct store to out.
#define CHUNKS 16
#define WAVE_LDS 2304          // 16 rows * 144 B
#define SMEM_BYTES 9216        // 4 waves staging; also covers 4*512*4 reduce

__global__ __launch_bounds__(256) void fused_kernel(const float* __restrict__ w,
                                                    const float* __restrict__ x,
                                                    float* __restrict__ apart,
                                                    uint4* __restrict__ xb,
                                                    float* __restrict__ out) {
    __shared__ char smem_raw[SMEM_BYTES];
    const int bid  = blockIdx.x;
    const int tid  = threadIdx.x;
    const int wv   = tid >> 6;
    const int lane = tid & 63;

    // ---- phase A: x conversion (blocks 0-63; 131072 floats total) ----
    if (bid < 64) {
        int i = bid * 256 + tid;
        const float4* x4 = (const float4*)x;
        float4 a0 = x4[i * 2];
        float4 a1 = x4[i * 2 + 1];
        uint4 o;
        o.x = bfr(a0.x) | (bfr(a0.y) << 16);
        o.y = bfr(a0.z) | (bfr(a0.w) << 16);
        o.z = bfr(a1.x) | (bfr(a1.y) << 16);
        o.w = bfr(a1.z) | (bfr(a1.w) << 16);
        xb[i] = o;
    }

    // ---- phase A: grid-stride abs-sum (exactly 172 iters/thread) ----
    {
        const float4* w4 = (const float4*)w;
        float s = 0.f;
#pragma unroll 4
        for (int i = bid * 256 + tid; i < NELEM_W / 4; i += NBLK * 256) {
            float4 v = w4[i];
            s += fabsf(v.x) + fabsf(v.y) + fabsf(v.z) + fabsf(v.w);
        }
        for (int off = 32; off > 0; off >>= 1)
            s += __shfl_down(s, off, 64);
        float* wsum = (float*)smem_raw;
        if (lane == 0) wsum[wv] = s;
        __syncthreads();
        if (tid == 0)
            apart[bid] = wsum[0] + wsum[1] + wsum[2] + wsum[3];
    }

    __threadfence();          // device-scope release of apart/xb
    cg::this_grid().sync();
    __threadfence();          // device-scope acquire

    // ---- phase B stage 1: thr/scale from 256 partials (1 load/thread) ----
    float s1 = apart[tid];
    for (int off = 32; off > 0; off >>= 1)
        s1 += __shfl_down(s1, off, 64);
    float* sred = (float*)smem_raw;
    __syncthreads();          // phase A done with smem
    if (lane == 0) sred[wv] = s1;
    __syncthreads();
    if (tid == 0) {
        double mean = (double)(sred[0] + sred[1] + sred[2] + sred[3]) / (double)NELEM_W;
        if (mean < 1e-5) mean = 1e-5;
        float mf = (float)mean;
        sred[4] = 0.7f * mf;
        sred[5] = mf;
    }
    __syncthreads();
    const float thr   = sred[4];
    const float scale = sred[5];
    __syncthreads();          // done reading sred before staging overwrites

    // ---- phase B stage 2: og-tile loop ----
    const int col  = lane & 15;     // fragment: output col in group / token
    const int quad = lane >> 4;     // fragment k sub-block; staging row group
    const int rlan = lane & 15;     // staging: 16-B slot within a row

    const int kw = wv * 1024;
    char* stage = smem_raw + wv * WAVE_LDS;
    char* wr    = stage + quad * 144 + rlan * 8;   // + j*576 per staging instr
    const char* rd = stage + col * 144;
    const __bf16* xbb = (const __bf16*)xb;
    const __bf16* xq  = xbb + (size_t)col * IN_F + kw + quad * 8;

    for (int og = bid; og < NOG; og += NBLK) {
        const float* wp = w + (size_t)(og * 16 + quad) * IN_F + kw + rlan * 4;

        f32x4 acc0 = {0.f, 0.f, 0.f, 0.f};
        f32x4 acc1 = {0.f, 0.f, 0.f, 0.f};

        float4 wbuf[2][4];
        bf16x8 xv[2][4];

#pragma unroll
        for (int c = 0; c < 2; ++c) {
            const float*  np = wp + c * 64;
            const __bf16* xn = xq + c * 64;
            wbuf[c][0] = *(const float4*)(np);
            wbuf[c][1] = *(const float4*)(np + 4 * IN_F);
            wbuf[c][2] = *(const float4*)(np + 8 * IN_F);
            wbuf[c][3] = *(const float4*)(np + 12 * IN_F);
            xv[c][0] = *(const bf16x8*)(xn);
            xv[c][1] = *(const bf16x8*)(xn + 32);
            xv[c][2] = *(const bf16x8*)(xn + 16 * IN_F);
            xv[c][3] = *(const bf16x8*)(xn + 16 * IN_F + 32);
        }

#define GEMM_BODY(c, cur)                                                      \
    {                                                                          \
        uint2 t0 = tern4(wbuf[cur][0], thr);                                   \
        uint2 t1 = tern4(wbuf[cur][1], thr);                                   \
        uint2 t2 = tern4(wbuf[cur][2], thr);                                   \
        uint2 t3 = tern4(wbuf[cur][3], thr);                                   \
        *(uint2*)(wr)        = t0;                                             \
        *(uint2*)(wr + 576)  = t1;                                             \
        *(uint2*)(wr + 1152) = t2;                                             \
        *(uint2*)(wr + 1728) = t3;                                             \
        bf16x8 a00 = xv[cur][0], a01 = xv[cur][1];                             \
        bf16x8 a10 = xv[cur][2], a11 = xv[cur][3];                             \
        if ((c) + 2 < CHUNKS) {                                                \
            const float*  np = wp + ((c) + 2) * 64;                            \
            const __bf16* xn = xq + ((c) + 2) * 64;                            \
            wbuf[cur][0] = *(const float4*)(np);                               \
            wbuf[cur][1] = *(const float4*)(np + 4 * IN_F);                    \
            wbuf[cur][2] = *(const float4*)(np + 8 * IN_F);                    \
            wbuf[cur][3] = *(const float4*)(np + 12 * IN_F);                   \
            xv[cur][0] = *(const bf16x8*)(xn);                                 \
            xv[cur][1] = *(const bf16x8*)(xn + 32);                            \
            xv[cur][2] = *(const bf16x8*)(xn + 16 * IN_F);                     \
            xv[cur][3] = *(const bf16x8*)(xn + 16 * IN_F + 32);                \
        }                                                                      \
        bf16x8 bw0 = *(const bf16x8*)(rd + quad * 16);                         \
        bf16x8 bw1 = *(const bf16x8*)(rd + 64 + quad * 16);                    \
        acc0 = __builtin_amdgcn_mfma_f32_16x16x32_bf16(a00, bw0, acc0, 0, 0, 0); \
        acc1 = __builtin_amdgcn_mfma_f32_16x16x32_bf16(a10, bw0, acc1, 0, 0, 0); \
        acc0 = __builtin_amdgcn_mfma_f32_16x16x32_bf16(a01, bw1, acc0, 0, 0, 0); \
        acc1 = __builtin_amdgcn_mfma_f32_16x16x32_bf16(a11, bw1, acc1, 0, 0, 0); \
    }

        for (int c = 0; c < CHUNKS; c += 2) {
            GEMM_BODY(c, 0)
            GEMM_BODY(c + 1, 1)
        }
#undef GEMM_BODY

        // tile epilogue: 4-wave reduce, direct store
        __syncthreads();
        float* red  = (float*)smem_raw;
        float* base = red + wv * 512;
#pragma unroll
        for (int r = 0; r < 4; ++r) base[r * 64 + lane]       = acc0[r];
#pragma unroll
        for (int r = 0; r < 4; ++r) base[256 + r * 64 + lane] = acc1[r];
        __syncthreads();

#pragma unroll
        for (int p = tid; p < 512; p += 256) {
            int t = p >> 4, cc = p & 15;
            int a = t >> 4;
            int q = (t >> 2) & 3;
            int r = t & 3;
            int idx = a * 256 + r * 64 + q * 16 + cc;
            float v = red[idx] + red[512 + idx] + red[1024 + idx] + red[1536 + idx];
            out[(size_t)t * OUT_F + og * 16 + cc] = v * scale;
        }
        __syncthreads();   // red reads done before next tile's staging writes
    }
}

extern "C" void kernel_launch(void* const* d_in, const int* in_sizes, int n_in,
                              void* d_out, int out_size, void* d_ws, size_t ws_size,
                              hipStream_t stream) {
    const float* x = (const float*)d_in[0];   // [32, 4096]
    const float* w = (const float*)d_in[1];   // [11008, 4096]
    float* out     = (float*)d_out;           // [32, 11008]
    char* ws       = (char*)d_ws;

    float* apart = (float*)(ws + APART_OFF);
    uint4* xb    = (uint4*)(ws + XB_OFF);

    void* args[] = { (void*)&w, (void*)&x, (void*)&apart, (void*)&xb, (void*)&out };
    hipLaunchCooperativeKernel((void*)fused_kernel, dim3(NBLK), dim3(256),
                               args, 0, stream);
}

// Round 9
// 301.444 us; speedup vs baseline: 1.1723x; 1.1723x over previous
//
#include <hip/hip_runtime.h>
#include <hip/hip_bf16.h>
#include <stdint.h>

#define IN_F 4096
#define OUT_F 11008
#define TOKENS 32
#define NELEM_W (OUT_F * IN_F)       // 45088768 weights, ~180 MB fp32
#define OUT_ELEMS (TOKENS * OUT_F)   // 352256

typedef __attribute__((ext_vector_type(8))) __bf16 bf16x8;
typedef __attribute__((ext_vector_type(4))) float  f32x4;

// d_ws layout (bytes):
//   [0, 64):           scalars: f[2]=threshold, f[3]=scale
//   [64, 64+256K):     xb  — x converted to bf16
//   [262208, +5.6M):   gemm split-K partials: 4 x 352256 f32
//   [5898304, +8K):    absum per-block partials: 2048 f32
#define XB_OFF    64
#define GPART_OFF 262208
#define APART_OFF 5898304
#define KSPLIT 4

// fp32 -> bf16 bits (round-to-nearest-even), result in low 16
__device__ __forceinline__ uint32_t bfr(float v) {
    uint32_t u = __float_as_uint(v);
    uint32_t r = u + 0x7FFFu + ((u >> 16) & 1u);
    return r >> 16;
}

// ---------------- pass 1: sum(|w|) partials + x->bf16 conversion ----------------
#define ABSUM_BLOCKS 2048
#define XCVT_BLOCKS  64

__global__ __launch_bounds__(256) void absum_xcvt_kernel(const float* __restrict__ w,
                                                         const float* __restrict__ x,
                                                         float* __restrict__ apart,
                                                         uint4* __restrict__ xb) {
    if (blockIdx.x >= ABSUM_BLOCKS) {
        int i = (blockIdx.x - ABSUM_BLOCKS) * 256 + threadIdx.x;
        const float4* x4 = (const float4*)x;
        float4 a0 = x4[i * 2];
        float4 a1 = x4[i * 2 + 1];
        uint4 o;
        o.x = bfr(a0.x) | (bfr(a0.y) << 16);
        o.y = bfr(a0.z) | (bfr(a0.w) << 16);
        o.z = bfr(a1.x) | (bfr(a1.y) << 16);
        o.w = bfr(a1.z) | (bfr(a1.w) << 16);
        xb[i] = o;
        return;
    }
    int tid = blockIdx.x * blockDim.x + threadIdx.x;
    int stride = ABSUM_BLOCKS * 256;
    const float4* w4 = (const float4*)w;
    const int n4 = NELEM_W / 4;
    float s = 0.f;
    for (int i = tid; i < n4; i += stride) {
        float4 v = w4[i];
        s += fabsf(v.x) + fabsf(v.y) + fabsf(v.z) + fabsf(v.w);
    }
    for (int off = 32; off > 0; off >>= 1)
        s += __shfl_down(s, off, 64);
    __shared__ float wsum[4];
    int lane = threadIdx.x & 63;
    int wv   = threadIdx.x >> 6;
    if (lane == 0) wsum[wv] = s;
    __syncthreads();
    if (threadIdx.x == 0)
        apart[blockIdx.x] = wsum[0] + wsum[1] + wsum[2] + wsum[3];
}

// ---------------- pass 1.5: reduce 2048 partials -> thr/scale ----------------
__global__ __launch_bounds__(256) void finalize_kernel(const float* __restrict__ apart,
                                                       float* __restrict__ wsf) {
    float s = 0.f;
#pragma unroll
    for (int j = 0; j < 8; ++j)
        s += apart[threadIdx.x + 256 * j];
    for (int off = 32; off > 0; off >>= 1)
        s += __shfl_down(s, off, 64);
    __shared__ float wsum[4];
    int lane = threadIdx.x & 63;
    int wv   = threadIdx.x >> 6;
    if (lane == 0) wsum[wv] = s;
    __syncthreads();
    if (threadIdx.x == 0) {
        double mean = (double)(wsum[0] + wsum[1] + wsum[2] + wsum[3]) / (double)NELEM_W;
        if (mean < 1e-5) mean = 1e-5;
        float mf = (float)mean;
        wsf[2] = 0.7f * mf;   // threshold
        wsf[3] = mf;          // scale
    }
}

// ---------------- ternarize helpers (verified) ----------------
__device__ __forceinline__ uint32_t tern1(float v, float thr) {
    uint32_t u  = __float_as_uint(v);
    uint32_t pm = (u & 0x80000000u) | 0x3F800000u;   // +-1.0f
    return (__builtin_fabsf(v) > thr) ? pm : 0u;
}

__device__ __forceinline__ uint2 tern4(float4 b, float thr) {
    uint32_t q0 = tern1(b.x, thr), q1 = tern1(b.y, thr);
    uint32_t q2 = tern1(b.z, thr), q3 = tern1(b.w, thr);
    uint2 r;
    r.x = __builtin_amdgcn_perm(q1, q0, 0x07060302u);
    r.y = __builtin_amdgcn_perm(q3, q2, 0x07060302u);
    return r;
}

// ---------------- pass 2: LDS-staged ternary GEMM, split-K=4 ----------------
// Grid: 688 o-groups x 4 K-quarters = 2752 blocks of 128 (2 waves) = 5504
// waves ~= 21.5/CU for latency hiding (R8 lesson: TLP is the lever).
// Wave wv covers 512 k in 8 chunks of 64. 2-deep register double-buffer.
// Partials -> d_ws (plain stores, no atomics).
#define CHUNKS 8
#define WAVE_LDS 2304          // 16 rows * 144 B
#define SMEM_BYTES 4608        // 2 waves; also covers 2*512*4 reduce buf

__global__ __launch_bounds__(128, 5) void ternary_gemm(const float* __restrict__ w,
                                                       const float* __restrict__ wsf,
                                                       const __bf16* __restrict__ xb,
                                                       float* __restrict__ gpart) {
    __shared__ char smem_raw[SMEM_BYTES];
    const float thr = wsf[2];
    const int og   = blockIdx.x >> 2;
    const int kq   = blockIdx.x & 3;
    const int tid  = threadIdx.x;
    const int wv   = tid >> 6;
    const int lane = tid & 63;
    const int col  = lane & 15;     // fragment: output col in group / token
    const int quad = lane >> 4;     // fragment k sub-block; staging row group
    const int rlan = lane & 15;     // staging: 16-B slot within a row

    const int kw = kq * 1024 + wv * 512;

    const float* wp = w + (size_t)(og * 16 + quad) * IN_F + kw + rlan * 4;
    char* stage = smem_raw + wv * WAVE_LDS;
    char* wr    = stage + quad * 144 + rlan * 8;   // + j*576 per staging instr
    const char* rd = stage + col * 144;
    const __bf16* xq = xb + (size_t)col * IN_F + kw + quad * 8;

    f32x4 acc0 = {0.f, 0.f, 0.f, 0.f};
    f32x4 acc1 = {0.f, 0.f, 0.f, 0.f};

    float4 wb[2][4];
    bf16x8 xv[2][4];

#pragma unroll
    for (int c = 0; c < 2; ++c) {
        const float*  np = wp + c * 64;
        const __bf16* xn = xq + c * 64;
        wb[c][0] = *(const float4*)(np);
        wb[c][1] = *(const float4*)(np + 4 * IN_F);
        wb[c][2] = *(const float4*)(np + 8 * IN_F);
        wb[c][3] = *(const float4*)(np + 12 * IN_F);
        xv[c][0] = *(const bf16x8*)(xn);
        xv[c][1] = *(const bf16x8*)(xn + 32);
        xv[c][2] = *(const bf16x8*)(xn + 16 * IN_F);
        xv[c][3] = *(const bf16x8*)(xn + 16 * IN_F + 32);
    }

#define GEMM_BODY(c, cur)                                                      \
    {                                                                          \
        uint2 t0 = tern4(wb[cur][0], thr);                                     \
        uint2 t1 = tern4(wb[cur][1], thr);                                     \
        uint2 t2 = tern4(wb[cur][2], thr);                                     \
        uint2 t3 = tern4(wb[cur][3], thr);                                     \
        *(uint2*)(wr)        = t0;                                             \
        *(uint2*)(wr + 576)  = t1;                                             \
        *(uint2*)(wr + 1152) = t2;                                             \
        *(uint2*)(wr + 1728) = t3;                                             \
        bf16x8 a00 = xv[cur][0], a01 = xv[cur][1];                             \
        bf16x8 a10 = xv[cur][2], a11 = xv[cur][3];                             \
        if ((c) + 2 < CHUNKS) {                                                \
            const float*  np = wp + ((c) + 2) * 64;                            \
            const __bf16* xn = xq + ((c) + 2) * 64;                            \
            wb[cur][0] = *(const float4*)(np);                                 \
            wb[cur][1] = *(const float4*)(np + 4 * IN_F);                      \
            wb[cur][2] = *(const float4*)(np + 8 * IN_F);                      \
            wb[cur][3] = *(const float4*)(np + 12 * IN_F);                     \
            xv[cur][0] = *(const bf16x8*)(xn);                                 \
            xv[cur][1] = *(const bf16x8*)(xn + 32);                            \
            xv[cur][2] = *(const bf16x8*)(xn + 16 * IN_F);                     \
            xv[cur][3] = *(const bf16x8*)(xn + 16 * IN_F + 32);                \
        }                                                                      \
        bf16x8 bw0 = *(const bf16x8*)(rd + quad * 16);                         \
        bf16x8 bw1 = *(const bf16x8*)(rd + 64 + quad * 16);                    \
        acc0 = __builtin_amdgcn_mfma_f32_16x16x32_bf16(a00, bw0, acc0, 0, 0, 0); \
        acc1 = __builtin_amdgcn_mfma_f32_16x16x32_bf16(a10, bw0, acc1, 0, 0, 0); \
        acc0 = __builtin_amdgcn_mfma_f32_16x16x32_bf16(a01, bw1, acc0, 0, 0, 0); \
        acc1 = __builtin_amdgcn_mfma_f32_16x16x32_bf16(a11, bw1, acc1, 0, 0, 0); \
    }

    for (int c = 0; c < CHUNKS; c += 2) {
        GEMM_BODY(c, 0)
        GEMM_BODY(c + 1, 1)
    }
#undef GEMM_BODY

    __syncthreads();
    float* red  = (float*)smem_raw;
    float* base = red + wv * 512;
#pragma unroll
    for (int r = 0; r < 4; ++r) base[r * 64 + lane]       = acc0[r];
#pragma unroll
    for (int r = 0; r < 4; ++r) base[256 + r * 64 + lane] = acc1[r];
    __syncthreads();

    // 512 outputs (32 tokens x 16 cols), 4 per thread, summed over 2 waves
    float* gp = gpart + (size_t)kq * OUT_ELEMS;
    for (int p = tid; p < 512; p += 128) {
        int t = p >> 4, cc = p & 15;
        int a = t >> 4;
        int q = (t >> 2) & 3;
        int r = t & 3;
        int idx = a * 256 + r * 64 + q * 16 + cc;
        gp[(size_t)t * OUT_F + og * 16 + cc] = red[idx] + red[512 + idx];
    }
}

// ---------------- pass 3: combine split-K partials ----------------
__global__ __launch_bounds__(256) void combine_kernel(const float* __restrict__ gpart,
                                                      const float* __restrict__ wsf,
                                                      float* __restrict__ out) {
    const float sc = wsf[3];
    int i = blockIdx.x * 256 + threadIdx.x;   // float4 index, 88064 total
    const float4* p0 = (const float4*)gpart;
    const float4* p1 = (const float4*)(gpart + OUT_ELEMS);
    const float4* p2 = (const float4*)(gpart + 2 * OUT_ELEMS);
    const float4* p3 = (const float4*)(gpart + 3 * OUT_ELEMS);
    float4 a = p0[i], b = p1[i], c = p2[i], d = p3[i];
    float4 o;
    o.x = ((a.x + b.x) + (c.x + d.x)) * sc;
    o.y = ((a.y + b.y) + (c.y + d.y)) * sc;
    o.z = ((a.z + b.z) + (c.z + d.z)) * sc;
    o.w = ((a.w + b.w) + (c.w + d.w)) * sc;
    ((float4*)out)[i] = o;
}

extern "C" void kernel_launch(void* const* d_in, const int* in_sizes, int n_in,
                              void* d_out, int out_size, void* d_ws, size_t ws_size,
                              hipStream_t stream) {
    const float* x = (const float*)d_in[0];   // [32, 4096]
    const float* w = (const float*)d_in[1];   // [11008, 4096]
    float* out     = (float*)d_out;           // [32, 11008]
    char* ws       = (char*)d_ws;

    float* wsf     = (float*)ws;
    uint4* xb      = (uint4*)(ws + XB_OFF);
    float* gpart   = (float*)(ws + GPART_OFF);
    float* apart   = (float*)(ws + APART_OFF);

    absum_xcvt_kernel<<<ABSUM_BLOCKS + XCVT_BLOCKS, 256, 0, stream>>>(w, x, apart, xb);
    finalize_kernel<<<1, 256, 0, stream>>>(apart, wsf);
    ternary_gemm<<<(OUT_F / 16) * KSPLIT, 128, 0, stream>>>(w, wsf, (const __bf16*)(ws + XB_OFF), gpart);
    combine_kernel<<<OUT_ELEMS / 4 / 256, 256, 0, stream>>>(gpart, wsf, out);
}